// Round 3
// baseline (656.473 us; speedup 1.0000x reference)
//
#include <hip/hip_runtime.h>
#include <hip/hip_bf16.h>
#include <math.h>

typedef __hip_bfloat16 bf16;

#define BATCH    8
#define DIM      128
#define NFRAMES  128
#define NSAMP    32768
#define NTAB     16
#define TSIZE    512

// dual-dtype input loader: inputs proven fp32 (rd1 NaN experiment) but keep
// runtime detection as a hedge.
__device__ __forceinline__ float ld(const void* p, int i, bool f32) {
    return f32 ? ((const float*)p)[i] : __bfloat162float(((const bf16*)p)[i]);
}

// workspace layout (float element offsets)
#define WS_VALUES 0        // 8 floats
#define WS_ENV    64       // 8*128 floats (env mlp output squared, per-frame)
#define WS_FREQ   1088     // 8*128 floats (freq mlp output squared, per-frame)
#define WS_SEL    2112     // 8*512 floats (normalized selected tables)
#define WS_PHASE  6208     // 8*32768 floats (phase in [0,1))
// total 268352 floats = 1.07 MB of ws

// ---------------------------------------------------------------------------
// K1: three tiny MLPs (one block per head). f64 accumulators (cheap at this
// size; keeps every head well inside tolerance).
// ---------------------------------------------------------------------------
__global__ __launch_bounds__(256) void k1_mlp(
    const void* __restrict__ x, const void* __restrict__ wav,
    const void* tw1, const void* tb1, const void* tw2, const void* tb2,
    const void* tw3, const void* tb3,
    const void* ew1, const void* eb1, const void* ew2, const void* eb2,
    const void* ew3, const void* eb3,
    const void* fw1, const void* fb1, const void* fw2, const void* fb2,
    const void* fw3, const void* fb3,
    float* __restrict__ ws)
{
    const int head = blockIdx.x;
    const int tid  = threadIdx.x;

    __shared__ int s_isf32;
    __shared__ float xs[BATCH*DIM];
    __shared__ float h1[BATCH*DIM];
    __shared__ float h2[BATCH*DIM];
    __shared__ float o3[BATCH*256];
    __shared__ float scores[BATCH*16];
    __shared__ int   idxs[BATCH];
    __shared__ float red[256];

    // dtype detection: x ~ N(0,1); genuine bf16 never has |v|>=32, fp32 bits
    // misread as bf16 do with overwhelming probability.
    if (tid == 0) s_isf32 = 0;
    __syncthreads();
    {
        const unsigned short* xb = (const unsigned short*)x;
        bool big = false;
        for (int i = tid; i < BATCH*DIM; i += 256) {
            const int e = (xb[i] >> 7) & 0xFF;
            if (e >= 132) big = true;
        }
        if (big) s_isf32 = 1;   // benign race: all writers store 1
    }
    __syncthreads();
    const bool F32 = (s_isf32 != 0);

    const void *W1, *B1, *W2, *B2, *W3, *B3;
    int od3;
    if (head == 0)      { W1=tw1; B1=tb1; W2=tw2; B2=tb2; W3=tw3; B3=tb3; od3=256; }
    else if (head == 1) { W1=ew1; B1=eb1; W2=ew2; B2=eb2; W3=ew3; B3=eb3; od3=128; }
    else                { W1=fw1; B1=fb1; W2=fw2; B2=fb2; W3=fw3; B3=fb3; od3=128; }

    for (int i = tid; i < BATCH*DIM; i += 256) xs[i] = ld(x, i, F32);
    __syncthreads();

    // ---- layer 1: (8x128)@(128x128)+b, leaky_relu 0.2 ----
    {
        const int o = tid & 127, bs = tid >> 7;
        double acc[4];
        const double bb = (double)ld(B1, o, F32);
        #pragma unroll
        for (int j = 0; j < 4; j++) acc[j] = bb;
        for (int k = 0; k < DIM; k++) {
            const float wv = ld(W1, k*DIM + o, F32);
            #pragma unroll
            for (int j = 0; j < 4; j++)
                acc[j] += (double)xs[(bs + 2*j)*DIM + k] * (double)wv;
        }
        #pragma unroll
        for (int j = 0; j < 4; j++) {
            float v = (float)acc[j];
            v = v > 0.f ? v : 0.2f*v;
            h1[(bs + 2*j)*DIM + o] = v;
        }
    }
    __syncthreads();

    // ---- layer 2 ----
    {
        const int o = tid & 127, bs = tid >> 7;
        double acc[4];
        const double bb = (double)ld(B2, o, F32);
        #pragma unroll
        for (int j = 0; j < 4; j++) acc[j] = bb;
        for (int k = 0; k < DIM; k++) {
            const float wv = ld(W2, k*DIM + o, F32);
            #pragma unroll
            for (int j = 0; j < 4; j++)
                acc[j] += (double)h1[(bs + 2*j)*DIM + k] * (double)wv;
        }
        #pragma unroll
        for (int j = 0; j < 4; j++) {
            float v = (float)acc[j];
            v = v > 0.f ? v : 0.2f*v;
            h2[(bs + 2*j)*DIM + o] = v;
        }
    }
    __syncthreads();

    // ---- layer 3 (linear) ----
    if (od3 == 256) {
        const int o = tid;
        double acc[8];
        const double bb = (double)ld(B3, o, F32);
        #pragma unroll
        for (int b = 0; b < 8; b++) acc[b] = bb;
        for (int k = 0; k < DIM; k++) {
            const float wv = ld(W3, k*256 + o, F32);
            #pragma unroll
            for (int b = 0; b < 8; b++)
                acc[b] += (double)h2[b*DIM + k] * (double)wv;
        }
        #pragma unroll
        for (int b = 0; b < 8; b++) o3[b*256 + o] = (float)acc[b];
    } else {
        const int o = tid & 127, bs = tid >> 7;
        double acc[4];
        const double bb = (double)ld(B3, o, F32);
        #pragma unroll
        for (int j = 0; j < 4; j++) acc[j] = bb;
        for (int k = 0; k < DIM; k++) {
            const float wv = ld(W3, k*DIM + o, F32);
            #pragma unroll
            for (int j = 0; j < 4; j++)
                acc[j] += (double)h2[(bs + 2*j)*DIM + k] * (double)wv;
        }
        #pragma unroll
        for (int j = 0; j < 4; j++) o3[(bs + 2*j)*DIM + o] = (float)acc[j];
    }
    __syncthreads();

    // ---- epilogues ----
    if (head == 0) {
        if (tid < 128) {
            const int b = tid >> 4, i = tid & 15;
            float s = 0.f;
            for (int j = 0; j < 16; j++) s += o3[b*256 + i*16 + j];
            scores[b*16 + i] = s * (1.0f/16.0f);
        }
        __syncthreads();
        if (tid < 8) {
            const int b = tid;
            float best = scores[b*16]; int bi = 0;
            for (int i = 1; i < 16; i++) {
                const float v = scores[b*16 + i];
                if (v > best) { best = v; bi = i; }  // first-max, as jnp.argmax
            }
            idxs[b] = bi;
            ws[WS_VALUES + b] = best;
        }
        __syncthreads();
        for (int b = 0; b < 8; b++) {
            const int idx = idxs[b];
            float m = -1e30f;
            for (int t = tid; t < TSIZE; t += 256)
                m = fmaxf(m, ld(wav, idx*TSIZE + t, F32));
            red[tid] = m;
            __syncthreads();
            for (int off = 128; off; off >>= 1) {
                if (tid < off) red[tid] = fmaxf(red[tid], red[tid + off]);
                __syncthreads();
            }
            const float mx = red[0] + 1e-8f;
            for (int t = tid; t < TSIZE; t += 256)
                ws[WS_SEL + b*TSIZE + t] = ld(wav, idx*TSIZE + t, F32) / mx;
            __syncthreads();
        }
    } else {
        float* dst = ws + (head == 1 ? WS_ENV : WS_FREQ);
        for (int i = tid; i < BATCH*NFRAMES; i += 256) {
            const float v = o3[i];
            dst[i] = v * v;   // square BEFORE interpolation, as reference
        }
    }
}

// ---------------------------------------------------------------------------
// K2: per-batch linear interp of freq^2 to 32768 samples + inclusive cumsum
// (f64 scan; freq ~5e-7 so any sane precision passes, f64 is free here).
// ---------------------------------------------------------------------------
__global__ __launch_bounds__(1024) void k2_phase(float* __restrict__ ws)
{
    const int b = blockIdx.x;
    const int t = threadIdx.x;
    __shared__ float  fr[NFRAMES];
    __shared__ double sums[1024];

    if (t < NFRAMES) fr[t] = ws[WS_FREQ + b*NFRAMES + t];
    __syncthreads();

    const int SPT = NSAMP / 1024;  // 32
    const int s0  = t * SPT;
    double v[32];
    double local = 0.0;
    #pragma unroll
    for (int i = 0; i < SPT; i++) {
        const int s = s0 + i;
        double pos = ((double)s + 0.5) * (1.0/256.0) - 0.5;
        pos = fmin(fmax(pos, 0.0), 127.0);
        const int lo = (int)pos;
        int hi = lo + 1; if (hi > 127) hi = 127;
        const double w = pos - (double)lo;
        const double f = (double)fr[lo] * (1.0 - w) + (double)fr[hi] * w;
        v[i] = f;
        local += f;
    }
    sums[t] = local;
    __syncthreads();

    for (int off = 1; off < 1024; off <<= 1) {
        const double add = (t >= off) ? sums[t - off] : 0.0;
        __syncthreads();
        sums[t] += add;
        __syncthreads();
    }

    double run = sums[t] - local;  // exclusive prefix
    float* phase = ws + WS_PHASE + (size_t)b * NSAMP;
    #pragma unroll
    for (int i = 0; i < SPT; i++) {
        run += v[i];
        phase[s0 + i] = (float)(run - floor(run));
    }
}

// ---------------------------------------------------------------------------
// K3: one wave per (b,s) row. Lane handles t = 4*lane + 256*j (j<2): two
// coalesced float4 stores (1 KiB/wave/instr) into the fp32 kernel matrix,
// plus wave-reduced table dot -> sampled.
// ---------------------------------------------------------------------------
__global__ __launch_bounds__(256) void k3_synth(const float* __restrict__ ws,
                                                float* __restrict__ out)
{
    const int lane = threadIdx.x & 63;
    const int row  = (blockIdx.x << 2) + (threadIdx.x >> 6);  // 4 waves/block
    const int b    = row >> 15;
    const int s    = row & (NSAMP - 1);

    const float p = ws[WS_PHASE + row];

    // env interp (align_corners=False), frames already squared
    float pos = ((float)s + 0.5f) * (1.0f/256.0f) - 0.5f;
    pos = fminf(fmaxf(pos, 0.0f), 127.0f);
    const int lo = (int)pos;
    int hi = lo + 1; if (hi > 127) hi = 127;
    const float w = pos - (float)lo;
    const float* envf = ws + WS_ENV + b*NFRAMES;
    const float env = envf[lo]*(1.0f - w) + envf[hi]*w;
    const float val = ws[WS_VALUES + b];

    float* krow = out + (size_t)BATCH*NSAMP + ((size_t)row << 9);  // fp32 elems
    const float* tab = ws + WS_SEL + b*TSIZE;

    float dot = 0.f;
    #pragma unroll
    for (int j = 0; j < 2; j++) {
        const int t0 = 4*lane + 256*j;
        const float4 tv = *reinterpret_cast<const float4*>(tab + t0);
        const float tb4[4] = {tv.x, tv.y, tv.z, tv.w};
        float pv[4];
        #pragma unroll
        for (int k = 0; k < 4; k++) {
            const float g = (float)(t0 + k) * (1.0f/511.0f);
            const float z = (g - p) * 100.0f;                    // /STD
            const float e = __expf(-0.5f*z*z) * 39.89422804014327f;
            dot += e * tb4[k];
            pv[k] = e;
        }
        float4 o4; o4.x = pv[0]; o4.y = pv[1]; o4.z = pv[2]; o4.w = pv[3];
        *reinterpret_cast<float4*>(krow + t0) = o4;
    }

    #pragma unroll
    for (int m = 32; m; m >>= 1) dot += __shfl_xor(dot, m, 64);
    if (lane == 0)
        out[row] = dot * env * val;   // sampled (output 0, fp32)
}

// ---------------------------------------------------------------------------
extern "C" void kernel_launch(void* const* d_in, const int* in_sizes, int n_in,
                              void* d_out, int out_size, void* d_ws, size_t ws_size,
                              hipStream_t stream)
{
    float* ws  = (float*)d_ws;
    float* out = (float*)d_out;   // fp32 outputs, per reference dtype

    hipLaunchKernelGGL(k1_mlp, dim3(3), dim3(256), 0, stream,
        d_in[0], d_in[1],
        d_in[2],  d_in[3],  d_in[4],  d_in[5],  d_in[6],  d_in[7],
        d_in[8],  d_in[9],  d_in[10], d_in[11], d_in[12], d_in[13],
        d_in[14], d_in[15], d_in[16], d_in[17], d_in[18], d_in[19],
        ws);

    hipLaunchKernelGGL(k2_phase, dim3(BATCH), dim3(1024), 0, stream, ws);

    hipLaunchKernelGGL(k3_synth, dim3((BATCH*NSAMP)/4), dim3(256), 0, stream,
        ws, out);
}

// Round 5
// 627.539 us; speedup vs baseline: 1.0461x; 1.0461x over previous
//
#include <hip/hip_runtime.h>
#include <hip/hip_bf16.h>
#include <math.h>

typedef __hip_bfloat16 bf16;
typedef float f32x4 __attribute__((ext_vector_type(4)));  // native vec for nt-store

#define BATCH    8
#define DIM      128
#define NFRAMES  128
#define NSAMP    32768
#define NTAB     16
#define TSIZE    512

// dual-dtype input loader (inputs measured fp32; bf16 hedge kept).
__device__ __forceinline__ float ld(const void* p, int i, bool f32) {
    return f32 ? ((const float*)p)[i] : __bfloat162float(((const bf16*)p)[i]);
}

// workspace layout (float element offsets)
#define WS_VALUES 0        // 8 floats
#define WS_ENV    64       // 8*128 env^2 frames
#define WS_FREQ   1088     // (unused, layout stability)
#define WS_SEL    2112     // 8*512 normalized selected tables
#define WS_PHASE  6208     // 8*32768 phase
// total 268352 floats = 1.07 MB

// ---------------------------------------------------------------------------
// KA: fused heads + phase. One block per batch item (8 blocks x 1024 thr).
// Each block: all three MLPs for its item (f64 acc), tc argmax + wavetable
// norm, env^2 frames, freq^2 -> interp -> f64 scan -> phase.
// ---------------------------------------------------------------------------
__global__ __launch_bounds__(1024) void kA_prep(
    const void* __restrict__ x, const void* __restrict__ wav,
    const void* tw1, const void* tb1, const void* tw2, const void* tb2,
    const void* tw3, const void* tb3,
    const void* ew1, const void* eb1, const void* ew2, const void* eb2,
    const void* ew3, const void* eb3,
    const void* fw1, const void* fb1, const void* fw2, const void* fb2,
    const void* fw3, const void* fb3,
    float* __restrict__ ws)
{
    const int b   = blockIdx.x;
    const int tid = threadIdx.x;

    __shared__ int    s_isf32;
    __shared__ float  xs[DIM];
    __shared__ float  h1s[3][DIM];
    __shared__ float  h2s[3][DIM];
    __shared__ float  o3tc[256];
    __shared__ float  envf[NFRAMES];
    __shared__ float  frf[NFRAMES];
    __shared__ float  scores[16];
    __shared__ float  red[512];
    __shared__ int    s_idx;
    __shared__ double sums[1024];

    // dtype detect: genuine bf16 N(0,1) never has |v|>=32; fp32 bits misread
    // as bf16 do with overwhelming probability.
    if (tid == 0) s_isf32 = 0;
    __syncthreads();
    {
        const unsigned short* xb = (const unsigned short*)x;
        if (tid < 1024) {
            const int e = (xb[tid] >> 7) & 0xFF;
            if (e >= 132) s_isf32 = 1;   // benign race
        }
    }
    __syncthreads();
    const bool F32 = (s_isf32 != 0);

    if (tid < DIM) xs[tid] = ld(x, b*DIM + tid, F32);
    __syncthreads();

    const void* W1h[3] = {tw1, ew1, fw1};
    const void* B1h[3] = {tb1, eb1, fb1};
    const void* W2h[3] = {tw2, ew2, fw2};
    const void* B2h[3] = {tb2, eb2, fb2};

    // ---- layer 1, all heads in parallel (384 threads) ----
    if (tid < 384) {
        const int head = tid >> 7, o = tid & 127;
        double acc = (double)ld(B1h[head], o, F32);
        const void* W = W1h[head];
        for (int k = 0; k < DIM; k++)
            acc += (double)xs[k] * (double)ld(W, k*DIM + o, F32);
        float v = (float)acc;
        h1s[head][o] = v > 0.f ? v : 0.2f*v;
    }
    __syncthreads();

    // ---- layer 2 ----
    if (tid < 384) {
        const int head = tid >> 7, o = tid & 127;
        double acc = (double)ld(B2h[head], o, F32);
        const void* W = W2h[head];
        const float* hh = h1s[head];
        for (int k = 0; k < DIM; k++)
            acc += (double)hh[k] * (double)ld(W, k*DIM + o, F32);
        float v = (float)acc;
        h2s[head][o] = v > 0.f ? v : 0.2f*v;
    }
    __syncthreads();

    // ---- layer 3 (tc: 256 outs, env/freq: 128 each; squared at write) ----
    if (tid < 256) {
        const int o = tid;
        double acc = (double)ld(tb3, o, F32);
        const float* hh = h2s[0];
        for (int k = 0; k < DIM; k++)
            acc += (double)hh[k] * (double)ld(tw3, k*256 + o, F32);
        o3tc[o] = (float)acc;
    } else if (tid < 384) {
        const int o = tid - 256;
        double acc = (double)ld(eb3, o, F32);
        const float* hh = h2s[1];
        for (int k = 0; k < DIM; k++)
            acc += (double)hh[k] * (double)ld(ew3, k*DIM + o, F32);
        const float v = (float)acc;
        envf[o] = v * v;                 // square BEFORE interpolation
    } else if (tid < 512) {
        const int o = tid - 384;
        double acc = (double)ld(fb3, o, F32);
        const float* hh = h2s[2];
        for (int k = 0; k < DIM; k++)
            acc += (double)hh[k] * (double)ld(fw3, k*DIM + o, F32);
        const float v = (float)acc;
        frf[o] = v * v;
    }
    __syncthreads();

    // ---- tc scores -> argmax ----
    if (tid < 16) {
        float s = 0.f;
        for (int j = 0; j < 16; j++) s += o3tc[tid*16 + j];
        scores[tid] = s * (1.0f/16.0f);
    }
    __syncthreads();
    if (tid == 0) {
        float best = scores[0]; int bi = 0;
        for (int i = 1; i < 16; i++)
            if (scores[i] > best) { best = scores[i]; bi = i; }  // first-max
        s_idx = bi;
        ws[WS_VALUES + b] = best;
    }
    __syncthreads();

    // ---- normalized selected wavetable ----
    const int idx = s_idx;
    float wv_t = 0.f;
    if (tid < 512) { wv_t = ld(wav, idx*TSIZE + tid, F32); red[tid] = wv_t; }
    __syncthreads();
    for (int off = 256; off; off >>= 1) {
        if (tid < off) red[tid] = fmaxf(red[tid], red[tid + off]);
        __syncthreads();
    }
    const float mx = red[0] + 1e-8f;
    if (tid < 512) ws[WS_SEL + b*TSIZE + tid] = wv_t / mx;
    if (tid < NFRAMES) ws[WS_ENV + b*NFRAMES + tid] = envf[tid];

    // ---- freq^2 interp -> f64 scan -> phase ----
    const int SPT = NSAMP / 1024;  // 32
    const int s0  = tid * SPT;
    double v[32];
    double local = 0.0;
    #pragma unroll
    for (int i = 0; i < SPT; i++) {
        const int s = s0 + i;
        double pos = ((double)s + 0.5) * (1.0/256.0) - 0.5;
        pos = fmin(fmax(pos, 0.0), 127.0);
        const int lo = (int)pos;
        int hi = lo + 1; if (hi > 127) hi = 127;
        const double w = pos - (double)lo;
        const double f = (double)frf[lo] * (1.0 - w) + (double)frf[hi] * w;
        v[i] = f;
        local += f;
    }
    sums[tid] = local;
    __syncthreads();
    for (int off = 1; off < 1024; off <<= 1) {
        const double add = (tid >= off) ? sums[tid - off] : 0.0;
        __syncthreads();
        sums[tid] += add;
        __syncthreads();
    }
    double run = sums[tid] - local;   // exclusive prefix
    float* phase = ws + WS_PHASE + (size_t)b * NSAMP;
    #pragma unroll
    for (int i = 0; i < SPT; i++) {
        run += v[i];
        phase[s0 + i] = (float)(run - floor(run));
    }
}

// ---------------------------------------------------------------------------
// KB: one wave per 4 consecutive rows. Table fragment (2 x f32x4/lane)
// hoisted across rows; nontemporal dwordx4 stores (write-once stream, skip
// L2 writeback pressure); packed f32x4 sampled-store from lane 0.
// ---------------------------------------------------------------------------
__global__ __launch_bounds__(256) void kB_synth(const float* __restrict__ ws,
                                                float* __restrict__ out)
{
    const int lane = threadIdx.x & 63;
    const int w    = (blockIdx.x << 2) + (threadIdx.x >> 6);
    const int r0   = w << 2;                 // 4 rows, never crosses batch
    const int b    = r0 >> 15;

    const float* tab = ws + WS_SEL + b*TSIZE;
    const f32x4 tv0 = *reinterpret_cast<const f32x4*>(tab + 4*lane);
    const f32x4 tv1 = *reinterpret_cast<const f32x4*>(tab + 4*lane + 256);
    const float  val  = ws[WS_VALUES + b];
    const float* envf = ws + WS_ENV + b*NFRAMES;
    float* kbase = out + (size_t)BATCH*NSAMP + ((size_t)r0 << 9);

    float samp[4];
    #pragma unroll
    for (int i = 0; i < 4; i++) {
        const int r = r0 + i;
        const int s = r & (NSAMP - 1);
        const float p = ws[WS_PHASE + r];

        float pos = ((float)s + 0.5f) * (1.0f/256.0f) - 0.5f;
        pos = fminf(fmaxf(pos, 0.0f), 127.0f);
        const int lo = (int)pos;
        int hi = lo + 1; if (hi > 127) hi = 127;
        const float wq = pos - (float)lo;
        const float env = envf[lo]*(1.0f - wq) + envf[hi]*wq;

        float dot = 0.f;
        #pragma unroll
        for (int j = 0; j < 2; j++) {
            const int t0 = 4*lane + 256*j;
            const f32x4 tv = j ? tv1 : tv0;
            f32x4 o4;
            #pragma unroll
            for (int k = 0; k < 4; k++) {
                const float g = (float)(t0 + k) * (1.0f/511.0f);
                const float z = (g - p) * 100.0f;                 // /STD
                const float e = __expf(-0.5f*z*z) * 39.89422804014327f;
                dot += e * tv[k];
                o4[k] = e;
            }
            __builtin_nontemporal_store(o4,
                reinterpret_cast<f32x4*>(kbase + (i << 9) + t0));
        }

        #pragma unroll
        for (int m = 32; m; m >>= 1) dot += __shfl_xor(dot, m, 64);
        samp[i] = dot * env * val;           // all lanes hold the full sum
    }

    if (lane == 0) {
        f32x4 s4; s4[0] = samp[0]; s4[1] = samp[1]; s4[2] = samp[2]; s4[3] = samp[3];
        *reinterpret_cast<f32x4*>(out + r0) = s4;   // r0 % 4 == 0 -> aligned
    }
}

// ---------------------------------------------------------------------------
extern "C" void kernel_launch(void* const* d_in, const int* in_sizes, int n_in,
                              void* d_out, int out_size, void* d_ws, size_t ws_size,
                              hipStream_t stream)
{
    float* ws  = (float*)d_ws;
    float* out = (float*)d_out;   // fp32 outputs per reference dtype

    hipLaunchKernelGGL(kA_prep, dim3(BATCH), dim3(1024), 0, stream,
        d_in[0], d_in[1],
        d_in[2],  d_in[3],  d_in[4],  d_in[5],  d_in[6],  d_in[7],
        d_in[8],  d_in[9],  d_in[10], d_in[11], d_in[12], d_in[13],
        d_in[14], d_in[15], d_in[16], d_in[17], d_in[18], d_in[19],
        ws);

    // 262144 rows / (4 rows/wave * 4 waves/block) = 16384 blocks
    hipLaunchKernelGGL(kB_synth, dim3((BATCH*NSAMP)/16), dim3(256), 0, stream,
        ws, out);
}